// Round 7
// baseline (79.500 us; speedup 1.0000x reference)
//
#include <hip/hip_runtime.h>
#include <math.h>

#define BB 1024
#define TT 196
#define NC 10
#define NB 4   // independent batch chains per thread

// DPP helper. quad_perm ctrl = sel0|sel1<<2|sel2<<4|sel3<<6; row_ror:N = 0x120|N
// row_ror:N semantics (GCN/CDNA): lane i reads lane (i-N) mod 16.
template <int CTRL>
__device__ __forceinline__ float dppf(float v) {
    return __int_as_float(__builtin_amdgcn_update_dpp(
        0, __float_as_int(v), CTRL, 0xF, 0xF, true));
}
#define QP_XOR3 0x1B   // quad: [3,2,1,0]
#define QP_XOR1 0xB1   // quad: [1,0,3,2]
#define QP_BC0  0x00   // quad: [0,0,0,0]
#define ROR4    0x124  // lane <- lane-4
#define ROR8    0x128  // lane <- lane-8
#define ROR12   0x12C  // lane <- lane-12 (= lane+4 mod 16)

__device__ __forceinline__ float rcp_f(float v) { return __builtin_amdgcn_rcpf(v); }
__device__ __forceinline__ float cos_rev(float v) { return __builtin_amdgcn_cosf(v); }

// ---------------- Kernel 1: quanvolution + angle-x-part precompute ----------------
// One thread per (b,t), t fastest. U/W reads wave-uniform -> scalar loads.
// Writes axp[b][t][16]: element q*4+g = (bias_g[q]+rx_g[q] + W_g[q][:]z) / 2pi.
__global__ void quanv_kernel(const float* __restrict__ x,
                             const float* __restrict__ U_re,
                             const float* __restrict__ U_im,
                             const float* __restrict__ Wf, const float* __restrict__ bf,
                             const float* __restrict__ Wi, const float* __restrict__ bi,
                             const float* __restrict__ Wg, const float* __restrict__ bg,
                             const float* __restrict__ Wo, const float* __restrict__ bo,
                             const float* __restrict__ rxf, const float* __restrict__ rxi,
                             const float* __restrict__ rxg, const float* __restrict__ rxo,
                             float* __restrict__ axp) {
    int tid = blockIdx.x * blockDim.x + threadIdx.x;
    if (tid >= BB * TT) return;
    int b = tid / TT;
    int t = tid - b * TT;
    int r = t / 14, c = t - r * 14;
    const float* img = x + (size_t)b * 784;

    float cc[4], ss[4];
    {
        float a0 = img[(2 * r) * 28 + 2 * c];
        float a1 = img[(2 * r) * 28 + 2 * c + 1];
        float a2 = img[(2 * r + 1) * 28 + 2 * c];
        float a3 = img[(2 * r + 1) * 28 + 2 * c + 1];
        __sincosf(0.5f * a0, &ss[0], &cc[0]);
        __sincosf(0.5f * a1, &ss[1], &cc[1]);
        __sincosf(0.5f * a2, &ss[2], &cc[2]);
        __sincosf(0.5f * a3, &ss[3], &cc[3]);
    }

    float a[16];
#pragma unroll
    for (int j = 0; j < 16; ++j) {
        float v = ((j >> 3) & 1) ? ss[0] : cc[0];
        v *= ((j >> 2) & 1) ? ss[1] : cc[1];
        v *= ((j >> 1) & 1) ? ss[2] : cc[2];
        v *= ((j >> 0) & 1) ? ss[3] : cc[3];
        a[j] = v;
    }

    float z0 = 0.f, z1 = 0.f, z2 = 0.f, z3 = 0.f;
#pragma unroll
    for (int j = 0; j < 16; ++j) {
        float vr = 0.f, vi = 0.f;
#pragma unroll
        for (int k = 0; k < 16; ++k) {
            vr = fmaf(U_re[j * 16 + k], a[k], vr);   // uniform addr -> s_load
            vi = fmaf(U_im[j * 16 + k], a[k], vi);
        }
        float p = vr * vr + vi * vi;
        z0 += ((j >> 3) & 1) ? -p : p;
        z1 += ((j >> 2) & 1) ? -p : p;
        z2 += ((j >> 1) & 1) ? -p : p;
        z3 += ((j >> 0) & 1) ? -p : p;
    }

    const float INV2PI = 0.15915494309189535f;
    float4* dst = reinterpret_cast<float4*>(axp + ((size_t)(b * TT + t) << 4));
#pragma unroll
    for (int q = 0; q < 4; ++q) {
        float vf = bf[q] + rxf[q];
        vf = fmaf(Wf[q*8+0], z0, vf); vf = fmaf(Wf[q*8+1], z1, vf);
        vf = fmaf(Wf[q*8+2], z2, vf); vf = fmaf(Wf[q*8+3], z3, vf);
        float vi = bi[q] + rxi[q];
        vi = fmaf(Wi[q*8+0], z0, vi); vi = fmaf(Wi[q*8+1], z1, vi);
        vi = fmaf(Wi[q*8+2], z2, vi); vi = fmaf(Wi[q*8+3], z3, vi);
        float vg = bg[q] + rxg[q];
        vg = fmaf(Wg[q*8+0], z0, vg); vg = fmaf(Wg[q*8+1], z1, vg);
        vg = fmaf(Wg[q*8+2], z2, vg); vg = fmaf(Wg[q*8+3], z3, vg);
        float vo = bo[q] + rxo[q];
        vo = fmaf(Wo[q*8+0], z0, vo); vo = fmaf(Wo[q*8+1], z1, vo);
        vo = fmaf(Wo[q*8+2], z2, vo); vo = fmaf(Wo[q*8+3], z3, vo);
        dst[q] = make_float4(vf * INV2PI, vi * INV2PI, vg * INV2PI, vo * INV2PI);
    }
}

// ---------------- Kernel 2: QLSTM, 16 lanes/batch, 4 chains/thread ----------------
// lane = q*4+g within each 16-lane group; 16-lane group g16 handles batches
// b_base + g16*4 + j for chains j=0..3. The 4 chains are independent; their
// per-step dependency chains interleave to hide VALU/trans/DPP latency.
// Per-step math identical to the R6-verified version:
//   e1=ror4(C)=C_{q-1}; aa=C*e1; e2=ror8(aa)=C_{q-2}C_{q-3}; e4=ror8(C)=C_{q-2}
//   q=0: z=e2*e1  q=1: z=aa  q=2: z=aa*e4  q=3: z=aa*e2
//   h: hq=BC0(o*tanh(c)); hh1=ror12(hq), hh2=ror8(hq), hh3=ror4(hq);
//   weights pre-permuted wh_k = W[q][4+((q+k)&3)].
__global__ __launch_bounds__(64) void qlstm16x4_kernel(
    const float* __restrict__ axp,
    const float* __restrict__ Wf, const float* __restrict__ Wi,
    const float* __restrict__ Wg, const float* __restrict__ Wo,
    const float* __restrict__ Wc, const float* __restrict__ bc,
    float* __restrict__ out) {
    int lane = threadIdx.x;          // 0..63
    int l16 = lane & 15;
    int g16 = lane >> 4;             // 0..3
    int q = l16 >> 2, g = l16 & 3;
    int bb = blockIdx.x * 16 + g16 * 4;   // chain j -> batch bb + j

    const float* W;
    if (g == 0)      W = Wf;
    else if (g == 1) W = Wi;
    else if (g == 2) W = Wg;
    else             W = Wo;

    const float INV2PI = 0.15915494309189535f;
    float wh0 = W[q * 8 + 4 + ((q + 0) & 3)] * INV2PI;
    float wh1 = W[q * 8 + 4 + ((q + 1) & 3)] * INV2PI;
    float wh2 = W[q * 8 + 4 + ((q + 2) & 3)] * INV2PI;
    float wh3 = W[q * 8 + 4 + ((q + 3) & 3)] * INV2PI;

    // Pade[5/4]: g==2 lane -> tanh(z); others -> sigma(z)=0.5+0.5*tanh(z/2)
    const bool tn = (g == 2);
    const float n0 = tn ? 945.f : 236.25f;
    const float n1 = tn ? 105.f : 6.5625f;
    const float n2 = tn ? 1.f   : 0.015625f;
    const float d1 = tn ? 420.f : 105.f;
    const float d2 = tn ? 15.f  : 0.9375f;
    const float kk = tn ? 0.f   : 0.5f;

    const bool q0 = (q == 0), q1 = (q == 1), q2 = (q == 2);

    float hh0[NB], hh1[NB], hh2[NB], hh3[NB], cs[NB];
#pragma unroll
    for (int j = 0; j < NB; ++j) {
        hh0[j] = hh1[j] = hh2[j] = hh3[j] = cs[j] = 0.f;
    }

    // chain j base: axp[(bb+j)*TT*16 + l16]; offset j*TT*16 is compile-time
    const float* base0 = axp + (((size_t)bb * TT) << 4) + l16;

    float xp[NB][14];
#pragma unroll
    for (int j = 0; j < NB; ++j)
#pragma unroll
        for (int s = 0; s < 14; ++s)
            xp[j][s] = base0[((size_t)s << 4) + (size_t)j * (TT * 16)];

    for (int it = 0; it < 14; ++it) {
        int itb = it * 14 + 14;   // absolute t of this iteration's prefetches
#pragma unroll
        for (int s = 0; s < 14; ++s) {
#pragma unroll
            for (int j = 0; j < NB; ++j) {
                float t0 = fmaf(wh0, hh0[j], xp[j][s]);
                float t1 = fmaf(wh3, hh3[j], wh2 * hh2[j]);
                float ang = fmaf(wh1, hh1[j], t0) + t1;
                float C = cos_rev(ang);
                float e1 = dppf<ROR4>(C);        // C_{q-1}
                float aa = C * e1;               // C_q C_{q-1}
                float e2 = dppf<ROR8>(aa);       // C_{q-2}C_{q-3}
                float e4 = dppf<ROR8>(C);        // C_{q-2}
                float A = q0 ? e2 : aa;
                float Bv = q0 ? e1 : (q1 ? 1.0f : (q2 ? e4 : e2));
                float z = A * Bv;
                float w2 = z * z;
                float nn = z * fmaf(w2, fmaf(w2, n2, n1), n0);
                float dd = fmaf(w2, fmaf(w2, d2, d1), 945.f);
                float val = fmaf(nn, rcp_f(dd), kk);
                float s1 = dppf<QP_XOR3>(val);
                float u  = val * s1;
                float s2 = dppf<QP_XOR1>(u);
                cs[j] = fmaf(val, cs[j], s2);    // valid at g==0
                float wc = cs[j] * cs[j];
                float na = cs[j] * fmaf(wc, fmaf(wc, 1.f, 105.f), 945.f);
                float da = fmaf(wc, fmaf(wc, 15.f, 420.f), 945.f);
                float th = na * rcp_f(da);
                float hq = dppf<QP_BC0>(s1 * th);    // h_q -> whole quad
                hh0[j] = hq;
                hh1[j] = dppf<ROR12>(hq);        // h_{q+1}
                hh2[j] = dppf<ROR8>(hq);         // h_{q+2}
                hh3[j] = dppf<ROR4>(hq);         // h_{q+3}
                int tnext = itb + s;
                int tp = tnext > (TT - 1) ? (TT - 1) : tnext;
                xp[j][s] = base0[((size_t)tp << 4) + (size_t)j * (TT * 16)];
            }
        }
    }

    // classifier + log_softmax: lane with l16==0 holds hh_k[j] = h_k of batch bb+j
    if (l16 == 0) {
#pragma unroll
        for (int j = 0; j < NB; ++j) {
            float l[NC];
            float mx = -1e30f;
#pragma unroll
            for (int k = 0; k < NC; ++k) {
                float v = bc[k];
                v = fmaf(Wc[k * 4 + 0], hh0[j], v);
                v = fmaf(Wc[k * 4 + 1], hh1[j], v);
                v = fmaf(Wc[k * 4 + 2], hh2[j], v);
                v = fmaf(Wc[k * 4 + 3], hh3[j], v);
                l[k] = v;
                mx = fmaxf(mx, v);
            }
            float se = 0.f;
#pragma unroll
            for (int k = 0; k < NC; ++k) se += __expf(l[k] - mx);
            float lse = mx + __logf(se);
#pragma unroll
            for (int k = 0; k < NC; ++k)
                out[(size_t)(bb + j) * NC + k] = l[k] - lse;
        }
    }
}

extern "C" void kernel_launch(void* const* d_in, const int* in_sizes, int n_in,
                              void* d_out, int out_size, void* d_ws, size_t ws_size,
                              hipStream_t stream) {
    (void)in_sizes; (void)n_in; (void)out_size; (void)ws_size;
    const float* x    = (const float*)d_in[0];
    const float* U_re = (const float*)d_in[1];
    const float* U_im = (const float*)d_in[2];
    const float* Wf   = (const float*)d_in[3];
    const float* bf   = (const float*)d_in[4];
    const float* Wi   = (const float*)d_in[5];
    const float* bi   = (const float*)d_in[6];
    const float* Wg   = (const float*)d_in[7];
    const float* bg   = (const float*)d_in[8];
    const float* Wo   = (const float*)d_in[9];
    const float* bo   = (const float*)d_in[10];
    const float* rxf  = (const float*)d_in[11];
    const float* rxi  = (const float*)d_in[12];
    const float* rxg  = (const float*)d_in[13];
    const float* rxo  = (const float*)d_in[14];
    const float* Wc   = (const float*)d_in[15];
    const float* bc   = (const float*)d_in[16];

    float* axp = (float*)d_ws;   // (B, T, 16) = 12.85 MB
    float* out = (float*)d_out;  // (B, 10)

    quanv_kernel<<<(BB * TT + 255) / 256, 256, 0, stream>>>(
        x, U_re, U_im, Wf, bf, Wi, bi, Wg, bg, Wo, bo,
        rxf, rxi, rxg, rxo, axp);
    qlstm16x4_kernel<<<BB / 16, 64, 0, stream>>>(
        axp, Wf, Wi, Wg, Wo, Wc, bc, out);
}

// Round 8
// 41.297 us; speedup vs baseline: 1.9251x; 1.9251x over previous
//
#include <hip/hip_runtime.h>
#include <math.h>

#define BB 1024
#define TT 196
#define NC 10

// DPP helper. quad_perm ctrl = sel0|sel1<<2|sel2<<4|sel3<<6; row_ror:N = 0x120|N
// row_ror:N semantics (GCN/CDNA): lane i reads lane (i-N) mod 16.
template <int CTRL>
__device__ __forceinline__ float dppf(float v) {
    return __int_as_float(__builtin_amdgcn_update_dpp(
        0, __float_as_int(v), CTRL, 0xF, 0xF, true));
}
#define QP_XOR3 0x1B   // quad: [3,2,1,0]
#define QP_XOR1 0xB1   // quad: [1,0,3,2]
#define QP_BC0  0x00   // quad: [0,0,0,0]
#define ROR4    0x124  // lane <- lane-4
#define ROR8    0x128  // lane <- lane-8
#define ROR12   0x12C  // lane <- lane-12 (= lane+4 mod 16)

__device__ __forceinline__ float cos_rev(float v) { return __builtin_amdgcn_cosf(v); }

// ---------------- Kernel 1: quanvolution + angle-x-part precompute ----------------
// One thread per (b,t), t fastest. U/W reads wave-uniform -> scalar loads.
// Writes axp[b][t][16]: element q*4+g = (bias_g[q]+rx_g[q] + W_g[q][:]z) / 2pi.
__global__ void quanv_kernel(const float* __restrict__ x,
                             const float* __restrict__ U_re,
                             const float* __restrict__ U_im,
                             const float* __restrict__ Wf, const float* __restrict__ bf,
                             const float* __restrict__ Wi, const float* __restrict__ bi,
                             const float* __restrict__ Wg, const float* __restrict__ bg,
                             const float* __restrict__ Wo, const float* __restrict__ bo,
                             const float* __restrict__ rxf, const float* __restrict__ rxi,
                             const float* __restrict__ rxg, const float* __restrict__ rxo,
                             float* __restrict__ axp) {
    int tid = blockIdx.x * blockDim.x + threadIdx.x;
    if (tid >= BB * TT) return;
    int b = tid / TT;
    int t = tid - b * TT;
    int r = t / 14, c = t - r * 14;
    const float* img = x + (size_t)b * 784;

    float cc[4], ss[4];
    {
        float a0 = img[(2 * r) * 28 + 2 * c];
        float a1 = img[(2 * r) * 28 + 2 * c + 1];
        float a2 = img[(2 * r + 1) * 28 + 2 * c];
        float a3 = img[(2 * r + 1) * 28 + 2 * c + 1];
        __sincosf(0.5f * a0, &ss[0], &cc[0]);
        __sincosf(0.5f * a1, &ss[1], &cc[1]);
        __sincosf(0.5f * a2, &ss[2], &cc[2]);
        __sincosf(0.5f * a3, &ss[3], &cc[3]);
    }

    float a[16];
#pragma unroll
    for (int j = 0; j < 16; ++j) {
        float v = ((j >> 3) & 1) ? ss[0] : cc[0];
        v *= ((j >> 2) & 1) ? ss[1] : cc[1];
        v *= ((j >> 1) & 1) ? ss[2] : cc[2];
        v *= ((j >> 0) & 1) ? ss[3] : cc[3];
        a[j] = v;
    }

    float z0 = 0.f, z1 = 0.f, z2 = 0.f, z3 = 0.f;
#pragma unroll
    for (int j = 0; j < 16; ++j) {
        float vr = 0.f, vi = 0.f;
#pragma unroll
        for (int k = 0; k < 16; ++k) {
            vr = fmaf(U_re[j * 16 + k], a[k], vr);   // uniform addr -> s_load
            vi = fmaf(U_im[j * 16 + k], a[k], vi);
        }
        float p = vr * vr + vi * vi;
        z0 += ((j >> 3) & 1) ? -p : p;
        z1 += ((j >> 2) & 1) ? -p : p;
        z2 += ((j >> 1) & 1) ? -p : p;
        z3 += ((j >> 0) & 1) ? -p : p;
    }

    const float INV2PI = 0.15915494309189535f;
    float4* dst = reinterpret_cast<float4*>(axp + ((size_t)(b * TT + t) << 4));
#pragma unroll
    for (int q = 0; q < 4; ++q) {
        float vf = bf[q] + rxf[q];
        vf = fmaf(Wf[q*8+0], z0, vf); vf = fmaf(Wf[q*8+1], z1, vf);
        vf = fmaf(Wf[q*8+2], z2, vf); vf = fmaf(Wf[q*8+3], z3, vf);
        float vi = bi[q] + rxi[q];
        vi = fmaf(Wi[q*8+0], z0, vi); vi = fmaf(Wi[q*8+1], z1, vi);
        vi = fmaf(Wi[q*8+2], z2, vi); vi = fmaf(Wi[q*8+3], z3, vi);
        float vg = bg[q] + rxg[q];
        vg = fmaf(Wg[q*8+0], z0, vg); vg = fmaf(Wg[q*8+1], z1, vg);
        vg = fmaf(Wg[q*8+2], z2, vg); vg = fmaf(Wg[q*8+3], z3, vg);
        float vo = bo[q] + rxo[q];
        vo = fmaf(Wo[q*8+0], z0, vo); vo = fmaf(Wo[q*8+1], z1, vo);
        vo = fmaf(Wo[q*8+2], z2, vo); vo = fmaf(Wo[q*8+3], z3, vo);
        dst[q] = make_float4(vf * INV2PI, vi * INV2PI, vg * INV2PI, vo * INV2PI);
    }
}

// ---------------- Kernel 2: QLSTM, 16 lanes per batch element ----------------
// lane = q*4+g. R6-proven structure; nonlinearities now division-free:
//   gate val: odd deg-7 poly (per-lane constants; z in [-1,1] provably)
//   tanh(c):  Pade[5/4] with cubic-seed + 1 Newton-step reciprocal
// Only transcendental on the recurrence chain is v_cos.
__global__ __launch_bounds__(64) void qlstm16_kernel(
    const float* __restrict__ axp,
    const float* __restrict__ Wf, const float* __restrict__ Wi,
    const float* __restrict__ Wg, const float* __restrict__ Wo,
    const float* __restrict__ Wc, const float* __restrict__ bc,
    float* __restrict__ out) {
    int tid = blockIdx.x * 64 + threadIdx.x;
    int b = tid >> 4;
    int l16 = tid & 15;
    int q = l16 >> 2, g = l16 & 3;

    const float* W;
    if (g == 0)      W = Wf;
    else if (g == 1) W = Wi;
    else if (g == 2) W = Wg;
    else             W = Wo;

    const float INV2PI = 0.15915494309189535f;
    float wh0 = W[q * 8 + 4 + ((q + 0) & 3)] * INV2PI;
    float wh1 = W[q * 8 + 4 + ((q + 1) & 3)] * INV2PI;
    float wh2 = W[q * 8 + 4 + ((q + 2) & 3)] * INV2PI;
    float wh3 = W[q * 8 + 4 + ((q + 3) & 3)] * INV2PI;

    // per-lane odd deg-7 poly: val = kk + z*(p1 + w(p3 + w(p5 + w*p7))), w=z^2
    // g==2: tanh(z) collocation fit on [-1,1]; others: sigma(z)=0.5+0.5*tanh(z/2) Taylor
    const bool tn = (g == 2);
    const float p1 = tn ? 0.9994157f  : 0.25f;
    const float p3 = tn ? -0.3269484f : -0.020833333f;
    const float p5 = tn ? 0.111770f   : 0.0020833333f;
    const float p7 = tn ? -0.022645f  : -4.216270e-4f;
    const float kk = tn ? 0.f         : 0.5f;

    // cubic seed for 1/(945+420w+15w^2), w in [0,4.84]
    const float K0 = 1.0582010e-3f;
    const float K1 = -4.0047e-4f;
    const float K2 = 8.4024e-5f;
    const float K3 = -6.949e-6f;

    const bool q0 = (q == 0), q1 = (q == 1), q2 = (q == 2);

    float hh0 = 0.f, hh1 = 0.f, hh2 = 0.f, hh3 = 0.f, c = 0.f;
    const float* base = axp + (((size_t)b * TT) << 4) + l16;

#define LDX(T) base[(size_t)(T) << 4]

#define STEP(XP, TNEXT)                                                       \
    {                                                                         \
        float t0 = fmaf(wh0, hh0, (XP));                                      \
        float t1 = fmaf(wh3, hh3, wh2 * hh2);                                 \
        float ang = fmaf(wh1, hh1, t0) + t1;                                  \
        float C = cos_rev(ang);                                               \
        float e1 = dppf<ROR4>(C);       /* C_{q-1} */                         \
        float aa = C * e1;              /* C_q C_{q-1} */                     \
        float e2 = dppf<ROR8>(aa);      /* C_{q-2}C_{q-3} */                  \
        float e4 = dppf<ROR8>(C);       /* C_{q-2} */                         \
        float A = q0 ? e2 : aa;                                               \
        float Bv = q0 ? e1 : (q1 ? 1.0f : (q2 ? e4 : e2));                    \
        float z = A * Bv;                                                     \
        float w2 = z * z;                                                     \
        float pv = fmaf(w2, fmaf(w2, fmaf(w2, p7, p5), p3), p1);              \
        float val = fmaf(z, pv, kk);                                          \
        float s1 = dppf<QP_XOR3>(val);                                        \
        float u  = val * s1;                                                  \
        float s2 = dppf<QP_XOR1>(u);                                          \
        c = fmaf(val, c, s2);           /* valid at g==0 */                   \
        float wc = c * c;                                                     \
        float na = c * fmaf(wc, fmaf(wc, 1.f, 105.f), 945.f);                 \
        float dd = fmaf(wc, fmaf(wc, 15.f, 420.f), 945.f);                    \
        float r0 = fmaf(wc, fmaf(wc, fmaf(wc, K3, K2), K1), K0);              \
        float r1 = r0 * fmaf(-dd, r0, 2.f);   /* Newton: ~6e-4 rel */         \
        float th = na * r1;                                                   \
        float hq = dppf<QP_BC0>(s1 * th);   /* h_q -> whole quad */           \
        hh0 = hq;                                                             \
        hh1 = dppf<ROR12>(hq);          /* h_{q+1} */                         \
        hh2 = dppf<ROR8>(hq);           /* h_{q+2} */                         \
        hh3 = dppf<ROR4>(hq);           /* h_{q+3} */                         \
        int tp = (TNEXT) > (TT - 1) ? (TT - 1) : (TNEXT);                     \
        (XP) = LDX(tp);                                                       \
    }

    float xp0  = LDX(0),  xp1  = LDX(1),  xp2  = LDX(2),  xp3  = LDX(3);
    float xp4  = LDX(4),  xp5  = LDX(5),  xp6  = LDX(6),  xp7  = LDX(7);
    float xp8  = LDX(8),  xp9  = LDX(9),  xp10 = LDX(10), xp11 = LDX(11);
    float xp12 = LDX(12), xp13 = LDX(13);

    for (int it = 0; it < 14; ++it) {
        int itb = it * 14 + 14;
        STEP(xp0,  itb + 0)
        STEP(xp1,  itb + 1)
        STEP(xp2,  itb + 2)
        STEP(xp3,  itb + 3)
        STEP(xp4,  itb + 4)
        STEP(xp5,  itb + 5)
        STEP(xp6,  itb + 6)
        STEP(xp7,  itb + 7)
        STEP(xp8,  itb + 8)
        STEP(xp9,  itb + 9)
        STEP(xp10, itb + 10)
        STEP(xp11, itb + 11)
        STEP(xp12, itb + 12)
        STEP(xp13, itb + 13)
    }
#undef STEP
#undef LDX

    // classifier + log_softmax: lane q=0,g=0 holds hh_k = h_k
    if (l16 == 0) {
        float l[NC];
        float mx = -1e30f;
#pragma unroll
        for (int k = 0; k < NC; ++k) {
            float v = bc[k];
            v = fmaf(Wc[k * 4 + 0], hh0, v);
            v = fmaf(Wc[k * 4 + 1], hh1, v);
            v = fmaf(Wc[k * 4 + 2], hh2, v);
            v = fmaf(Wc[k * 4 + 3], hh3, v);
            l[k] = v;
            mx = fmaxf(mx, v);
        }
        float se = 0.f;
#pragma unroll
        for (int k = 0; k < NC; ++k) se += __expf(l[k] - mx);
        float lse = mx + __logf(se);
#pragma unroll
        for (int k = 0; k < NC; ++k) out[(size_t)b * NC + k] = l[k] - lse;
    }
}

extern "C" void kernel_launch(void* const* d_in, const int* in_sizes, int n_in,
                              void* d_out, int out_size, void* d_ws, size_t ws_size,
                              hipStream_t stream) {
    (void)in_sizes; (void)n_in; (void)out_size; (void)ws_size;
    const float* x    = (const float*)d_in[0];
    const float* U_re = (const float*)d_in[1];
    const float* U_im = (const float*)d_in[2];
    const float* Wf   = (const float*)d_in[3];
    const float* bf   = (const float*)d_in[4];
    const float* Wi   = (const float*)d_in[5];
    const float* bi   = (const float*)d_in[6];
    const float* Wg   = (const float*)d_in[7];
    const float* bg   = (const float*)d_in[8];
    const float* Wo   = (const float*)d_in[9];
    const float* bo   = (const float*)d_in[10];
    const float* rxf  = (const float*)d_in[11];
    const float* rxi  = (const float*)d_in[12];
    const float* rxg  = (const float*)d_in[13];
    const float* rxo  = (const float*)d_in[14];
    const float* Wc   = (const float*)d_in[15];
    const float* bc   = (const float*)d_in[16];

    float* axp = (float*)d_ws;   // (B, T, 16) = 12.85 MB
    float* out = (float*)d_out;  // (B, 10)

    quanv_kernel<<<(BB * TT + 255) / 256, 256, 0, stream>>>(
        x, U_re, U_im, Wf, bf, Wi, bi, Wg, bg, Wo, bo,
        rxf, rxi, rxg, rxo, axp);
    qlstm16_kernel<<<(BB * 16) / 64, 64, 0, stream>>>(
        axp, Wf, Wi, Wg, Wo, Wc, bc, out);
}